// Round 4
// baseline (1110.609 us; speedup 1.0000x reference)
//
#include <hip/hip_runtime.h>
#include <math.h>

#define B_ 8
#define S_ 1024
#define D_ 4096
#define DV_ 1024
#define NP_ 576
#define MAXE_ 1599
#define PK_ 588          // 3*14*14
#define KP_ 608          // PK_ padded to multiple of 32
#define IMG_ 336
#define GRID_ 24
#define PATCH_ 14
#define IMAGE_TOKEN_ 32000
#define PAD_TOKEN_ 0
#define NLAYERS_ 32
#define NEXP_ 8
#define NSH_ 2

// ---- output layout (flat float32) ----
#define EMB_ELEMS ((size_t)B_ * MAXE_ * D_)
#define OFF_EMB   ((size_t)1)
#define OFF_ATTN  (OFF_EMB + EMB_ELEMS)
#define OFF_LAB   (OFF_ATTN + (size_t)B_ * MAXE_)
#define OFF_ROUTER (OFF_LAB + (size_t)B_ * MAXE_)
#define ROUTER_ELEMS ((size_t)NLAYERS_ * MAXE_ * (NEXP_ + NSH_))

typedef __bf16 bf16x8 __attribute__((ext_vector_type(8)));
typedef float  f32x4  __attribute__((ext_vector_type(4)));
typedef unsigned short ushort_t;

__device__ __forceinline__ unsigned short f2bf(float f) {
    unsigned u = __float_as_uint(f);
    u += 0x7fffu + ((u >> 16) & 1u);   // RNE
    return (unsigned short)(u >> 16);
}

__device__ __forceinline__ float bf2f(unsigned short u) {
    return __uint_as_float((unsigned)u << 16);
}

__device__ __forceinline__ void async_copy16(const void* g, void* l) {
    __builtin_amdgcn_global_load_lds(
        (const __attribute__((address_space(1))) void*)g,
        (__attribute__((address_space(3))) void*)l, 16, 0, 0);
}

__global__ void fill_tail_kernel(float* __restrict__ out) {
    size_t i = (size_t)blockIdx.x * blockDim.x + threadIdx.x;
    if (i == 0) out[0] = 0.0f;
    for (size_t j = i; j < ROUTER_ELEMS; j += (size_t)gridDim.x * blockDim.x)
        out[OFF_ROUTER + j] = 0.0f;
}

// Single block, 512 threads (8 waves). Wave w handles batch row w.
__global__ __launch_bounds__(512) void merge_kernel(
    const int* __restrict__ input_ids, const int* __restrict__ attn_mask,
    const int* __restrict__ labels, float* __restrict__ out,
    int* __restrict__ src_index, int* __restrict__ img_pos)
{
    __shared__ int sh_nbpad[B_];
    __shared__ int sh_shift[B_];
    __shared__ int sh_nqual[B_];
    __shared__ int sh_leftpad;
    float* out_attn = out + OFF_ATTN;
    float* out_lab  = out + OFF_LAB;
    const int tid = threadIdx.x;

    for (int i = tid; i < B_ * MAXE_; i += blockDim.x) {
        src_index[i] = -1;
        out_attn[i] = 0.0f;
        out_lab[i] = -100.0f;
    }
    for (int i = tid; i < B_ * NP_; i += blockDim.x) img_pos[i] = -1;
    if (tid == 0) {
        int anypad = 0;
        for (int b = 0; b < B_; b++)
            if (input_ids[b * S_ + S_ - 1] == PAD_TOKEN_) anypad = 1;
        sh_leftpad = !anypad;
    }
    __syncthreads();

    const int wave = tid >> 6;
    const int lane = tid & 63;
    const unsigned long long below = (1ull << lane) - 1ull;

    if (wave < B_) {
        const int b = wave;
        int nspec = 0;
        for (int c = 0; c < S_; c += 64) {
            int id = input_ids[b * S_ + c + lane];
            nspec += __popcll(__ballot(id == IMAGE_TOKEN_));
        }
        int nb_pad = MAXE_ - S_ - (NP_ - 1) * nspec;
        int shift = sh_leftpad ? nb_pad : 0;
        int nholes = MAXE_ - (S_ - nspec);
        int nq = nholes - nb_pad; if (nq < 0) nq = 0;
        if (lane == 0) { sh_nbpad[b] = nb_pad; sh_shift[b] = shift; sh_nqual[b] = nq; }
        int carry = 0;
        for (int c = 0; c < S_; c += 64) {
            int t = c + lane;
            int id = input_ids[b * S_ + t];
            int spec = (id == IMAGE_TOKEN_);
            unsigned long long m = __ballot(spec);
            int nbefore = carry + __popcll(m & below);
            if (!spec) {
                int pos = t + (NP_ - 1) * nbefore + shift;
                if (pos >= 0 && pos < MAXE_) {
                    src_index[b * MAXE_ + pos] = t;
                    out_attn[b * MAXE_ + pos] = (float)attn_mask[b * S_ + t];
                    out_lab[b * MAXE_ + pos]  = (float)labels[b * S_ + t];
                }
            }
            carry += __popcll(m);
        }
    }
    __syncthreads();

    if (wave < B_) {
        const int b = wave;
        int offs = 0;
        for (int r = 0; r < b; r++) offs += sh_nqual[r];
        const int nb_pad = sh_nbpad[b];
        int hcarry = 0;
        for (int c = 0; c < MAXE_; c += 64) {
            int p = c + lane;
            int flag = 0;
            if (p < MAXE_) flag = (src_index[b * MAXE_ + p] == -1);
            unsigned long long m = __ballot(flag);
            int h = hcarry + __popcll(m & below);
            if (flag && h >= nb_pad) {
                int g = offs + (h - nb_pad);
                if (g > B_ * NP_ - 1) g = B_ * NP_ - 1;
                if (g < 0) g = 0;
                img_pos[g] = b * MAXE_ + p;
                src_index[b * MAXE_ + p] = -2;
                out_attn[b * MAXE_ + p] = 1.0f;
            }
            hcarry += __popcll(m);
        }
    }
}

// patchify + fp32 -> (bf16 hi, bf16 lo residual) split, K padded to KP_
__global__ void patchify_split_kernel(const float* __restrict__ pix,
                                      ushort_t* __restrict__ xh,
                                      ushort_t* __restrict__ xl)
{
    int i = blockIdx.x * blockDim.x + threadIdx.x;
    const int total = B_ * NP_ * KP_;
    if (i >= total) return;
    int q = i % KP_;
    int t = (i / KP_) % NP_;
    int n = i / (KP_ * NP_);
    float v = 0.0f;
    if (q < PK_) {
        int c = q / (PATCH_ * PATCH_);
        int r = q % (PATCH_ * PATCH_);
        int py = r / PATCH_, px = r % PATCH_;
        int gy = t / GRID_, gx = t % GRID_;
        v = pix[(((size_t)n * 3 + c) * IMG_ + gy * PATCH_ + py) * IMG_ + gx * PATCH_ + px];
    }
    ushort_t h = f2bf(v);
    xh[i] = h;
    xl[i] = f2bf(v - bf2f(h));
}

// transpose + fp32->bf16 convert: src[R][C] -> dst[C][R]
__global__ __launch_bounds__(256) void transpose_bf16_kernel(
    const float* __restrict__ src, ushort_t* __restrict__ dst, int R, int C)
{
    __shared__ float tile[32][33];
    int c0 = blockIdx.x * 32, r0 = blockIdx.y * 32;
    int tx = threadIdx.x & 31, ty = threadIdx.x >> 5;   // 32 x 8
    for (int i = ty; i < 32; i += 8)
        tile[i][tx] = src[(size_t)(r0 + i) * C + c0 + tx];
    __syncthreads();
    for (int i = ty; i < 32; i += 8)
        dst[(size_t)(c0 + i) * R + r0 + tx] = f2bf(tile[tx][i]);
}

// transpose + hi/lo bf16 split: src[R][C] fp32 -> dh/dl [C][RP] (rows >= R zero)
__global__ __launch_bounds__(256) void transpose_split_kernel(
    const float* __restrict__ src, ushort_t* __restrict__ dh,
    ushort_t* __restrict__ dl, int R, int C, int RP)
{
    __shared__ float tile[32][33];
    int c0 = blockIdx.x * 32, r0 = blockIdx.y * 32;
    int tx = threadIdx.x & 31, ty = threadIdx.x >> 5;   // 32 x 8
    for (int i = ty; i < 32; i += 8) {
        float v = 0.0f;
        if (r0 + i < R && c0 + tx < C) v = src[(size_t)(r0 + i) * C + c0 + tx];
        tile[i][tx] = v;
    }
    __syncthreads();
    for (int i = ty; i < 32; i += 8) {
        if (c0 + i < C && r0 + tx < RP) {
            float v = tile[tx][i];
            ushort_t h = f2bf(v);
            dh[(size_t)(c0 + i) * RP + r0 + tx] = h;
            dl[(size_t)(c0 + i) * RP + r0 + tx] = f2bf(v - bf2f(h));
        }
    }
}

// Split-precision MFMA GEMM (fp32-accurate via bf16 hi/lo, 3 passes):
// C[M][N] = (Ah+Al)[M][K] @ (Bh+Bl)[N][K]^T + bias, dropping Al*Bl (~2^-18 rel).
// 128x128 / BK=32 / 4-wave. bf16 output.
__global__ __launch_bounds__(256) void mfma_gemm_split(
    const ushort_t* __restrict__ Ah, const ushort_t* __restrict__ Al,
    const ushort_t* __restrict__ Bth, const ushort_t* __restrict__ Btl,
    const float* __restrict__ bias, ushort_t* __restrict__ outb,
    int M, int N, int K)
{
    __shared__ ushort_t Ash[128 * 32];
    __shared__ ushort_t Asl[128 * 32];
    __shared__ ushort_t Bsh[128 * 32];
    __shared__ ushort_t Bsl[128 * 32];
    const int tid  = threadIdx.x;
    const int wave = tid >> 6;
    const int lane = tid & 63;
    const int l16  = lane & 15;
    const int quad = lane >> 4;
    const int wrow = (wave >> 1) * 64;
    const int wcol = (wave & 1) * 64;
    const int row0 = blockIdx.y * 128;
    const int col0 = blockIdx.x * 128;

    f32x4 acc[4][4];
#pragma unroll
    for (int i = 0; i < 4; i++)
#pragma unroll
        for (int j = 0; j < 4; j++) acc[i][j] = (f32x4)(0.0f);

    const int R0a = wave * 32;
    const int lr  = lane >> 2;
    const int lc  = (lane & 3) * 8;

    for (int k0 = 0; k0 < K; k0 += 32) {
#pragma unroll
        for (int i = 0; i < 2; i++) {
            int R0 = R0a + i * 16;
            size_t aoff = (size_t)(row0 + R0 + lr) * K + k0 + lc;
            size_t boff = (size_t)(col0 + R0 + lr) * K + k0 + lc;
            async_copy16(Ah  + aoff, &Ash[R0 * 32]);
            async_copy16(Al  + aoff, &Asl[R0 * 32]);
            async_copy16(Bth + boff, &Bsh[R0 * 32]);
            async_copy16(Btl + boff, &Bsl[R0 * 32]);
        }
        __syncthreads();

        bf16x8 ah[4], al[4], bh[4], bl[4];
#pragma unroll
        for (int mt = 0; mt < 4; mt++) {
            ah[mt] = *(const bf16x8*)&Ash[(wrow + mt * 16 + l16) * 32 + quad * 8];
            al[mt] = *(const bf16x8*)&Asl[(wrow + mt * 16 + l16) * 32 + quad * 8];
        }
#pragma unroll
        for (int nt = 0; nt < 4; nt++) {
            bh[nt] = *(const bf16x8*)&Bsh[(wcol + nt * 16 + l16) * 32 + quad * 8];
            bl[nt] = *(const bf16x8*)&Bsl[(wcol + nt * 16 + l16) * 32 + quad * 8];
        }
#pragma unroll
        for (int mt = 0; mt < 4; mt++)
#pragma unroll
            for (int nt = 0; nt < 4; nt++) {
                acc[mt][nt] = __builtin_amdgcn_mfma_f32_16x16x32_bf16(
                    ah[mt], bh[nt], acc[mt][nt], 0, 0, 0);
                acc[mt][nt] = __builtin_amdgcn_mfma_f32_16x16x32_bf16(
                    ah[mt], bl[nt], acc[mt][nt], 0, 0, 0);
                acc[mt][nt] = __builtin_amdgcn_mfma_f32_16x16x32_bf16(
                    al[mt], bh[nt], acc[mt][nt], 0, 0, 0);
            }
        __syncthreads();
    }

    float bv[4];
#pragma unroll
    for (int nt = 0; nt < 4; nt++) bv[nt] = bias[col0 + wcol + nt * 16 + l16];

#pragma unroll
    for (int mt = 0; mt < 4; mt++) {
#pragma unroll
        for (int r = 0; r < 4; r++) {
            int row = row0 + wrow + mt * 16 + quad * 4 + r;
            ushort_t* dst = outb + (size_t)row * N;
#pragma unroll
            for (int nt = 0; nt < 4; nt++) {
                int col = col0 + wcol + nt * 16 + l16;
                dst[col] = f2bf(acc[mt][nt][r] + bv[nt]);
            }
        }
    }
}

// bf16 MFMA GEMM, B-transposed: C[M][N] = A[M][K] @ Bt[N][K]^T  (+bias)
// 128x128 tile, BK=64, XOR-swizzled LDS (chunk ^= row&7; fed by inverse-swizzled
// global source since global_load_lds writes linearly), XCD-aware 1D grid.
// mode 1: gelu(acc+bias) -> bf16 outb ; mode 2: acc+bias -> f32 outf scattered
__global__ __launch_bounds__(256) void mfma_gemm_bt(
    const ushort_t* __restrict__ A, const ushort_t* __restrict__ Bt,
    const float* __restrict__ bias, ushort_t* __restrict__ outb,
    float* __restrict__ outf, const int* __restrict__ pos_map,
    int M, int N, int K, int mode)
{
    __shared__ ushort_t As[128 * 64];   // 16 KB, row = 64 ushort = 128 B = 8 chunks
    __shared__ ushort_t Bs[128 * 64];
    const int tid  = threadIdx.x;
    const int wave = tid >> 6;
    const int lane = tid & 63;
    const int l16  = lane & 15;
    const int quad = lane >> 4;
    const int wrow = (wave >> 1) * 64;
    const int wcol = (wave & 1) * 64;

    // XCD-aware bijective swizzle of linear block id (requires nwg % 8 == 0)
    int nwg = gridDim.x;
    int bid = blockIdx.x;
    if ((nwg & 7) == 0) {
        int cpx = nwg >> 3;
        bid = (bid & 7) * cpx + (bid >> 3);
    }
    const int nbx = N >> 7;            // column-blocks
    const int row0 = (bid / nbx) * 128;
    const int col0 = (bid % nbx) * 128;

    f32x4 acc[4][4];
#pragma unroll
    for (int i = 0; i < 4; i++)
#pragma unroll
        for (int j = 0; j < 4; j++) acc[i][j] = (f32x4)(0.0f);

    // staging: per wave 4 A-issues + 4 B-issues; each issue = 8 rows x 128 B.
    // lane l -> row = R0 + (l>>3), dest chunk = l&7 (linear LDS).
    // source column chunk = (l&7) ^ (l>>3)  [inverse swizzle, row&7 == l>>3]
    const int srow = lane >> 3;                       // 0..7
    const int scol = 8 * ((lane & 7) ^ srow);         // swizzled col offset (ushorts)

    for (int k0 = 0; k0 < K; k0 += 64) {
#pragma unroll
        for (int i = 0; i < 4; i++) {
            int R0 = wave * 32 + i * 8;
            const ushort_t* ga = A  + (size_t)(row0 + R0 + srow) * K + k0 + scol;
            const ushort_t* gb = Bt + (size_t)(col0 + R0 + srow) * K + k0 + scol;
            async_copy16(ga, &As[R0 * 64]);
            async_copy16(gb, &Bs[R0 * 64]);
        }
        __syncthreads();

        bf16x8 af[4][2], bf[4][2];
#pragma unroll
        for (int s = 0; s < 2; s++) {
#pragma unroll
            for (int mt = 0; mt < 4; mt++) {
                int r = wrow + mt * 16 + l16;
                int pc = ((s << 2) + quad) ^ (l16 & 7);   // swizzled read chunk
                af[mt][s] = *(const bf16x8*)&As[r * 64 + pc * 8];
            }
#pragma unroll
            for (int nt = 0; nt < 4; nt++) {
                int r = wcol + nt * 16 + l16;
                int pc = ((s << 2) + quad) ^ (l16 & 7);
                bf[nt][s] = *(const bf16x8*)&Bs[r * 64 + pc * 8];
            }
        }
#pragma unroll
        for (int s = 0; s < 2; s++)
#pragma unroll
            for (int mt = 0; mt < 4; mt++)
#pragma unroll
                for (int nt = 0; nt < 4; nt++)
                    acc[mt][nt] = __builtin_amdgcn_mfma_f32_16x16x32_bf16(
                        af[mt][s], bf[nt][s], acc[mt][nt], 0, 0, 0);
        __syncthreads();
    }

    float bv[4];
#pragma unroll
    for (int nt = 0; nt < 4; nt++) bv[nt] = bias[col0 + wcol + nt * 16 + l16];

#pragma unroll
    for (int mt = 0; mt < 4; mt++) {
#pragma unroll
        for (int r = 0; r < 4; r++) {
            int row = row0 + wrow + mt * 16 + quad * 4 + r;
            if (mode == 2) {
                int orow = pos_map[row];
                if (orow < 0) continue;
#pragma unroll
                for (int nt = 0; nt < 4; nt++) {
                    int col = col0 + wcol + nt * 16 + l16;
                    outf[(size_t)orow * N + col] = acc[mt][nt][r] + bv[nt];
                }
            } else {
#pragma unroll
                for (int nt = 0; nt < 4; nt++) {
                    int col = col0 + wcol + nt * 16 + l16;
                    float x = acc[mt][nt][r] + bv[nt];
                    // gelu(tanh approx) == x * sigmoid(2u); one v_exp_f32
                    float u = 0.7978845608028654f * (x + 0.044715f * x * x * x);
                    x = x / (1.0f + __expf(-2.0f * u));
                    outb[(size_t)row * N + col] = f2bf(x);
                }
            }
        }
    }
}

__global__ __launch_bounds__(256) void scatter_text_kernel(
    const int* __restrict__ src_index, const int* __restrict__ input_ids,
    const float* __restrict__ embed, float* __restrict__ final_emb)
{
    int row = blockIdx.x;
    int src = src_index[row];
    if (src == -2) return;   // image row, written by GEMM3
    float4* dst = (float4*)(final_emb + (size_t)row * D_);
    if (src >= 0) {
        int b = row / MAXE_;
        int tok = input_ids[b * S_ + src];
        const float4* s = (const float4*)(embed + (size_t)tok * D_);
#pragma unroll
        for (int i = threadIdx.x; i < D_ / 4; i += 256) dst[i] = s[i];
    } else {
#pragma unroll
        for (int i = threadIdx.x; i < D_ / 4; i += 256)
            dst[i] = make_float4(0.f, 0.f, 0.f, 0.f);
    }
}

extern "C" void kernel_launch(void* const* d_in, const int* in_sizes, int n_in,
                              void* d_out, int out_size, void* d_ws, size_t ws_size,
                              hipStream_t stream)
{
    const int*   input_ids = (const int*)d_in[0];
    const float* pixel     = (const float*)d_in[1];
    const int*   attn      = (const int*)d_in[2];
    const int*   labels    = (const int*)d_in[3];
    const float* embed     = (const float*)d_in[4];
    const float* patch_w   = (const float*)d_in[6];
    const float* patch_b   = (const float*)d_in[7];
    const float* w1        = (const float*)d_in[8];
    const float* b1        = (const float*)d_in[9];
    const float* w2        = (const float*)d_in[10];
    const float* b2        = (const float*)d_in[11];
    float* out = (float*)d_out;

    // workspace layout (all 16B-aligned)
    char* w = (char*)d_ws;
    int* src_index = (int*)w;                                    // 51200 B
    int* img_pos   = (int*)(w + 51200);                          // 18432 B
    ushort_t* xh   = (ushort_t*)(w + 51200 + 18432);             // 4608*608 bf16
    ushort_t* xl   = xh  + (size_t)B_ * NP_ * KP_;               // 4608*608 bf16
    ushort_t* pwh  = xl  + (size_t)B_ * NP_ * KP_;               // 1024*608 bf16
    ushort_t* pwl  = pwh + (size_t)DV_ * KP_;                    // 1024*608 bf16
    ushort_t* hbuf = pwl + (size_t)DV_ * KP_;                    // 4608*1024 bf16
    ushort_t* g1   = hbuf + (size_t)B_ * NP_ * DV_;              // 4608*4096 bf16
    ushort_t* w1t  = g1 + (size_t)B_ * NP_ * D_;                 // 4096*1024 bf16
    ushort_t* w2t  = w1t + (size_t)D_ * DV_;                     // 4096*4096 bf16

    fill_tail_kernel<<<2048, 256, 0, stream>>>(out);
    merge_kernel<<<1, 512, 0, stream>>>(input_ids, attn, labels, out, src_index, img_pos);

    {
        int total = B_ * NP_ * KP_;
        patchify_split_kernel<<<(total + 255) / 256, 256, 0, stream>>>(pixel, xh, xl);
    }
    // patch_w (588x1024) -> hi/lo bf16 [1024][608]
    transpose_split_kernel<<<dim3(DV_ / 32, KP_ / 32), 256, 0, stream>>>(
        patch_w, pwh, pwl, PK_, DV_, KP_);
    // weight converts: w1 (DVxD) -> w1t (DxDV), w2 (DxD) -> w2t (DxD)
    transpose_bf16_kernel<<<dim3(D_ / 32, DV_ / 32), 256, 0, stream>>>(w1, w1t, DV_, D_);
    transpose_bf16_kernel<<<dim3(D_ / 32, D_ / 32), 256, 0, stream>>>(w2, w2t, D_, D_);

    const int M = B_ * NP_;  // 4608
    // GEMM1 (split bf16 MFMA, ~fp32 accurate): x @ patch_w + patch_b -> hbuf bf16
    mfma_gemm_split<<<dim3(DV_ / 128, M / 128), 256, 0, stream>>>(
        xh, xl, pwh, pwl, patch_b, hbuf, M, DV_, KP_);
    // GEMM2 (MFMA, BK=64+swz): gelu(h @ w1 + b1) -> g1 bf16
    mfma_gemm_bt<<<(D_ / 128) * (M / 128), 256, 0, stream>>>(
        hbuf, w1t, b1, g1, nullptr, nullptr, M, D_, DV_, 1);
    // GEMM3 (MFMA, BK=64+swz): g1 @ w2 + b2 -> scattered fp32 rows of final_emb
    mfma_gemm_bt<<<(D_ / 128) * (M / 128), 256, 0, stream>>>(
        g1, w2t, b2, nullptr, out + OFF_EMB, img_pos, M, D_, D_, 2);

    scatter_text_kernel<<<B_ * MAXE_, 256, 0, stream>>>(src_index, input_ids, embed, out + OFF_EMB);
}

// Round 5
// 1085.055 us; speedup vs baseline: 1.0236x; 1.0236x over previous
//
#include <hip/hip_runtime.h>
#include <math.h>

#define B_ 8
#define S_ 1024
#define D_ 4096
#define DV_ 1024
#define NP_ 576
#define MAXE_ 1599
#define PK_ 588          // 3*14*14
#define KP_ 608          // PK_ padded to multiple of 32
#define IMG_ 336
#define GRID_ 24
#define PATCH_ 14
#define IMAGE_TOKEN_ 32000
#define PAD_TOKEN_ 0
#define NLAYERS_ 32
#define NEXP_ 8
#define NSH_ 2

// ---- output layout (flat float32) ----
#define EMB_ELEMS ((size_t)B_ * MAXE_ * D_)
#define OFF_EMB   ((size_t)1)
#define OFF_ATTN  (OFF_EMB + EMB_ELEMS)
#define OFF_LAB   (OFF_ATTN + (size_t)B_ * MAXE_)
#define OFF_ROUTER (OFF_LAB + (size_t)B_ * MAXE_)
#define ROUTER_ELEMS ((size_t)NLAYERS_ * MAXE_ * (NEXP_ + NSH_))

typedef __bf16 bf16x8 __attribute__((ext_vector_type(8)));
typedef float  f32x4  __attribute__((ext_vector_type(4)));
typedef unsigned short ushort_t;

__device__ __forceinline__ unsigned short f2bf(float f) {
    unsigned u = __float_as_uint(f);
    u += 0x7fffu + ((u >> 16) & 1u);   // RNE
    return (unsigned short)(u >> 16);
}

__device__ __forceinline__ float bf2f(unsigned short u) {
    return __uint_as_float((unsigned)u << 16);
}

__device__ __forceinline__ void async_copy16(const void* g, void* l) {
    __builtin_amdgcn_global_load_lds(
        (const __attribute__((address_space(1))) void*)g,
        (__attribute__((address_space(3))) void*)l, 16, 0, 0);
}

__global__ void fill_tail_kernel(float* __restrict__ out) {
    size_t i = (size_t)blockIdx.x * blockDim.x + threadIdx.x;
    if (i == 0) out[0] = 0.0f;
    for (size_t j = i; j < ROUTER_ELEMS; j += (size_t)gridDim.x * blockDim.x)
        out[OFF_ROUTER + j] = 0.0f;
}

// Single block, 512 threads (8 waves). Wave w handles batch row w.
__global__ __launch_bounds__(512) void merge_kernel(
    const int* __restrict__ input_ids, const int* __restrict__ attn_mask,
    const int* __restrict__ labels, float* __restrict__ out,
    int* __restrict__ src_index, int* __restrict__ img_pos)
{
    __shared__ int sh_nbpad[B_];
    __shared__ int sh_shift[B_];
    __shared__ int sh_nqual[B_];
    __shared__ int sh_leftpad;
    float* out_attn = out + OFF_ATTN;
    float* out_lab  = out + OFF_LAB;
    const int tid = threadIdx.x;

    for (int i = tid; i < B_ * MAXE_; i += blockDim.x) {
        src_index[i] = -1;
        out_attn[i] = 0.0f;
        out_lab[i] = -100.0f;
    }
    for (int i = tid; i < B_ * NP_; i += blockDim.x) img_pos[i] = -1;
    if (tid == 0) {
        int anypad = 0;
        for (int b = 0; b < B_; b++)
            if (input_ids[b * S_ + S_ - 1] == PAD_TOKEN_) anypad = 1;
        sh_leftpad = !anypad;
    }
    __syncthreads();

    const int wave = tid >> 6;
    const int lane = tid & 63;
    const unsigned long long below = (1ull << lane) - 1ull;

    if (wave < B_) {
        const int b = wave;
        int nspec = 0;
        for (int c = 0; c < S_; c += 64) {
            int id = input_ids[b * S_ + c + lane];
            nspec += __popcll(__ballot(id == IMAGE_TOKEN_));
        }
        int nb_pad = MAXE_ - S_ - (NP_ - 1) * nspec;
        int shift = sh_leftpad ? nb_pad : 0;
        int nholes = MAXE_ - (S_ - nspec);
        int nq = nholes - nb_pad; if (nq < 0) nq = 0;
        if (lane == 0) { sh_nbpad[b] = nb_pad; sh_shift[b] = shift; sh_nqual[b] = nq; }
        int carry = 0;
        for (int c = 0; c < S_; c += 64) {
            int t = c + lane;
            int id = input_ids[b * S_ + t];
            int spec = (id == IMAGE_TOKEN_);
            unsigned long long m = __ballot(spec);
            int nbefore = carry + __popcll(m & below);
            if (!spec) {
                int pos = t + (NP_ - 1) * nbefore + shift;
                if (pos >= 0 && pos < MAXE_) {
                    src_index[b * MAXE_ + pos] = t;
                    out_attn[b * MAXE_ + pos] = (float)attn_mask[b * S_ + t];
                    out_lab[b * MAXE_ + pos]  = (float)labels[b * S_ + t];
                }
            }
            carry += __popcll(m);
        }
    }
    __syncthreads();

    if (wave < B_) {
        const int b = wave;
        int offs = 0;
        for (int r = 0; r < b; r++) offs += sh_nqual[r];
        const int nb_pad = sh_nbpad[b];
        int hcarry = 0;
        for (int c = 0; c < MAXE_; c += 64) {
            int p = c + lane;
            int flag = 0;
            if (p < MAXE_) flag = (src_index[b * MAXE_ + p] == -1);
            unsigned long long m = __ballot(flag);
            int h = hcarry + __popcll(m & below);
            if (flag && h >= nb_pad) {
                int g = offs + (h - nb_pad);
                if (g > B_ * NP_ - 1) g = B_ * NP_ - 1;
                if (g < 0) g = 0;
                img_pos[g] = b * MAXE_ + p;
                src_index[b * MAXE_ + p] = -2;
                out_attn[b * MAXE_ + p] = 1.0f;
            }
            hcarry += __popcll(m);
        }
    }
}

// patchify + fp32 -> (bf16 hi, bf16 lo residual) split, K padded to KP_
__global__ void patchify_split_kernel(const float* __restrict__ pix,
                                      ushort_t* __restrict__ xh,
                                      ushort_t* __restrict__ xl)
{
    int i = blockIdx.x * blockDim.x + threadIdx.x;
    const int total = B_ * NP_ * KP_;
    if (i >= total) return;
    int q = i % KP_;
    int t = (i / KP_) % NP_;
    int n = i / (KP_ * NP_);
    float v = 0.0f;
    if (q < PK_) {
        int c = q / (PATCH_ * PATCH_);
        int r = q % (PATCH_ * PATCH_);
        int py = r / PATCH_, px = r % PATCH_;
        int gy = t / GRID_, gx = t % GRID_;
        v = pix[(((size_t)n * 3 + c) * IMG_ + gy * PATCH_ + py) * IMG_ + gx * PATCH_ + px];
    }
    ushort_t h = f2bf(v);
    xh[i] = h;
    xl[i] = f2bf(v - bf2f(h));
}

// transpose + fp32->bf16 convert: src[R][C] -> dst[C][R]
// write phase vectorized: ushort2 stores (2x store width vs scalar ushort)
__global__ __launch_bounds__(256) void transpose_bf16_kernel(
    const float* __restrict__ src, ushort_t* __restrict__ dst, int R, int C)
{
    __shared__ float tile[32][33];
    int c0 = blockIdx.x * 32, r0 = blockIdx.y * 32;
    int tx = threadIdx.x & 31, ty = threadIdx.x >> 5;   // 32 x 8
    for (int i = ty; i < 32; i += 8)
        tile[i][tx] = src[(size_t)(r0 + i) * C + c0 + tx];
    __syncthreads();
    int j = threadIdx.x & 15;        // output col-pair within tile row
    int k = threadIdx.x >> 4;        // 0..15 output-row index
#pragma unroll
    for (int p = 0; p < 2; p++) {
        int i = k + p * 16;          // output row within tile (= src col)
        ushort2 v;
        v.x = f2bf(tile[2 * j][i]);
        v.y = f2bf(tile[2 * j + 1][i]);
        *(ushort2*)&dst[(size_t)(c0 + i) * R + r0 + 2 * j] = v;
    }
}

// transpose + hi/lo bf16 split: src[R][C] fp32 -> dh/dl [C][RP] (rows >= R zero)
__global__ __launch_bounds__(256) void transpose_split_kernel(
    const float* __restrict__ src, ushort_t* __restrict__ dh,
    ushort_t* __restrict__ dl, int R, int C, int RP)
{
    __shared__ float tile[32][33];
    int c0 = blockIdx.x * 32, r0 = blockIdx.y * 32;
    int tx = threadIdx.x & 31, ty = threadIdx.x >> 5;   // 32 x 8
    for (int i = ty; i < 32; i += 8) {
        float v = 0.0f;
        if (r0 + i < R && c0 + tx < C) v = src[(size_t)(r0 + i) * C + c0 + tx];
        tile[i][tx] = v;
    }
    __syncthreads();
    for (int i = ty; i < 32; i += 8) {
        if (c0 + i < C && r0 + tx < RP) {
            float v = tile[tx][i];
            ushort_t h = f2bf(v);
            dh[(size_t)(c0 + i) * RP + r0 + tx] = h;
            dl[(size_t)(c0 + i) * RP + r0 + tx] = f2bf(v - bf2f(h));
        }
    }
}

// Split-precision MFMA GEMM (fp32-accurate via bf16 hi/lo, 3 passes):
// C[M][N] = (Ah+Al)[M][K] @ (Bh+Bl)[N][K]^T + bias, dropping Al*Bl (~2^-18 rel).
// 128x128 / BK=32 / 4-wave. bf16 output.
__global__ __launch_bounds__(256) void mfma_gemm_split(
    const ushort_t* __restrict__ Ah, const ushort_t* __restrict__ Al,
    const ushort_t* __restrict__ Bth, const ushort_t* __restrict__ Btl,
    const float* __restrict__ bias, ushort_t* __restrict__ outb,
    int M, int N, int K)
{
    __shared__ ushort_t Ash[128 * 32];
    __shared__ ushort_t Asl[128 * 32];
    __shared__ ushort_t Bsh[128 * 32];
    __shared__ ushort_t Bsl[128 * 32];
    const int tid  = threadIdx.x;
    const int wave = tid >> 6;
    const int lane = tid & 63;
    const int l16  = lane & 15;
    const int quad = lane >> 4;
    const int wrow = (wave >> 1) * 64;
    const int wcol = (wave & 1) * 64;
    const int row0 = blockIdx.y * 128;
    const int col0 = blockIdx.x * 128;

    f32x4 acc[4][4];
#pragma unroll
    for (int i = 0; i < 4; i++)
#pragma unroll
        for (int j = 0; j < 4; j++) acc[i][j] = (f32x4)(0.0f);

    const int R0a = wave * 32;
    const int lr  = lane >> 2;
    const int lc  = (lane & 3) * 8;

    for (int k0 = 0; k0 < K; k0 += 32) {
#pragma unroll
        for (int i = 0; i < 2; i++) {
            int R0 = R0a + i * 16;
            size_t aoff = (size_t)(row0 + R0 + lr) * K + k0 + lc;
            size_t boff = (size_t)(col0 + R0 + lr) * K + k0 + lc;
            async_copy16(Ah  + aoff, &Ash[R0 * 32]);
            async_copy16(Al  + aoff, &Asl[R0 * 32]);
            async_copy16(Bth + boff, &Bsh[R0 * 32]);
            async_copy16(Btl + boff, &Bsl[R0 * 32]);
        }
        __syncthreads();

        bf16x8 ah[4], al[4], bh[4], bl[4];
#pragma unroll
        for (int mt = 0; mt < 4; mt++) {
            ah[mt] = *(const bf16x8*)&Ash[(wrow + mt * 16 + l16) * 32 + quad * 8];
            al[mt] = *(const bf16x8*)&Asl[(wrow + mt * 16 + l16) * 32 + quad * 8];
        }
#pragma unroll
        for (int nt = 0; nt < 4; nt++) {
            bh[nt] = *(const bf16x8*)&Bsh[(wcol + nt * 16 + l16) * 32 + quad * 8];
            bl[nt] = *(const bf16x8*)&Bsl[(wcol + nt * 16 + l16) * 32 + quad * 8];
        }
#pragma unroll
        for (int mt = 0; mt < 4; mt++)
#pragma unroll
            for (int nt = 0; nt < 4; nt++) {
                acc[mt][nt] = __builtin_amdgcn_mfma_f32_16x16x32_bf16(
                    ah[mt], bh[nt], acc[mt][nt], 0, 0, 0);
                acc[mt][nt] = __builtin_amdgcn_mfma_f32_16x16x32_bf16(
                    ah[mt], bl[nt], acc[mt][nt], 0, 0, 0);
                acc[mt][nt] = __builtin_amdgcn_mfma_f32_16x16x32_bf16(
                    al[mt], bh[nt], acc[mt][nt], 0, 0, 0);
            }
        __syncthreads();
    }

    float bv[4];
#pragma unroll
    for (int nt = 0; nt < 4; nt++) bv[nt] = bias[col0 + wcol + nt * 16 + l16];

#pragma unroll
    for (int mt = 0; mt < 4; mt++) {
#pragma unroll
        for (int r = 0; r < 4; r++) {
            int row = row0 + wrow + mt * 16 + quad * 4 + r;
            ushort_t* dst = outb + (size_t)row * N;
#pragma unroll
            for (int nt = 0; nt < 4; nt++) {
                int col = col0 + wcol + nt * 16 + l16;
                dst[col] = f2bf(acc[mt][nt][r] + bv[nt]);
            }
        }
    }
}

// bf16 MFMA GEMM, B-transposed: C[M][N] = A[M][K] @ Bt[N][K]^T  (+bias)
// 128x128 tile, BK=32, 256 threads = 4 waves in 2x2, 16x16x32 MFMA.
// mode 1: gelu(acc+bias) -> bf16 outb ; mode 2: acc+bias -> f32 outf scattered
__global__ __launch_bounds__(256) void mfma_gemm_bt(
    const ushort_t* __restrict__ A, const ushort_t* __restrict__ Bt,
    const float* __restrict__ bias, ushort_t* __restrict__ outb,
    float* __restrict__ outf, const int* __restrict__ pos_map,
    int M, int N, int K, int mode)
{
    __shared__ ushort_t As[128 * 32];
    __shared__ ushort_t Bs[128 * 32];
    const int tid  = threadIdx.x;
    const int wave = tid >> 6;
    const int lane = tid & 63;
    const int l16  = lane & 15;
    const int quad = lane >> 4;
    const int wrow = (wave >> 1) * 64;
    const int wcol = (wave & 1) * 64;
    const int row0 = blockIdx.y * 128;
    const int col0 = blockIdx.x * 128;

    f32x4 acc[4][4];
#pragma unroll
    for (int i = 0; i < 4; i++)
#pragma unroll
        for (int j = 0; j < 4; j++) acc[i][j] = (f32x4)(0.0f);

    const int R0a = wave * 32;
    const int lr  = lane >> 2;
    const int lc  = (lane & 3) * 8;

    for (int k0 = 0; k0 < K; k0 += 32) {
#pragma unroll
        for (int i = 0; i < 2; i++) {
            int R0 = R0a + i * 16;
            const ushort_t* ga = A  + (size_t)(row0 + R0 + lr) * K + k0 + lc;
            const ushort_t* gb = Bt + (size_t)(col0 + R0 + lr) * K + k0 + lc;
            async_copy16(ga, &As[R0 * 32]);
            async_copy16(gb, &Bs[R0 * 32]);
        }
        __syncthreads();

        bf16x8 af[4], bf[4];
#pragma unroll
        for (int mt = 0; mt < 4; mt++)
            af[mt] = *(const bf16x8*)&As[(wrow + mt * 16 + l16) * 32 + quad * 8];
#pragma unroll
        for (int nt = 0; nt < 4; nt++)
            bf[nt] = *(const bf16x8*)&Bs[(wcol + nt * 16 + l16) * 32 + quad * 8];
#pragma unroll
        for (int mt = 0; mt < 4; mt++)
#pragma unroll
            for (int nt = 0; nt < 4; nt++)
                acc[mt][nt] = __builtin_amdgcn_mfma_f32_16x16x32_bf16(
                    af[mt], bf[nt], acc[mt][nt], 0, 0, 0);
        __syncthreads();
    }

    float bv[4];
#pragma unroll
    for (int nt = 0; nt < 4; nt++) bv[nt] = bias[col0 + wcol + nt * 16 + l16];

#pragma unroll
    for (int mt = 0; mt < 4; mt++) {
#pragma unroll
        for (int r = 0; r < 4; r++) {
            int row = row0 + wrow + mt * 16 + quad * 4 + r;
            if (mode == 2) {
                int orow = pos_map[row];
                if (orow < 0) continue;
#pragma unroll
                for (int nt = 0; nt < 4; nt++) {
                    int col = col0 + wcol + nt * 16 + l16;
                    outf[(size_t)orow * N + col] = acc[mt][nt][r] + bv[nt];
                }
            } else {
#pragma unroll
                for (int nt = 0; nt < 4; nt++) {
                    int col = col0 + wcol + nt * 16 + l16;
                    float x = acc[mt][nt][r] + bv[nt];
                    // gelu(tanh approx) == x * sigmoid(2u); one v_exp_f32
                    float u = 0.7978845608028654f * (x + 0.044715f * x * x * x);
                    x = x / (1.0f + __expf(-2.0f * u));
                    outb[(size_t)row * N + col] = f2bf(x);
                }
            }
        }
    }
}

__global__ __launch_bounds__(256) void scatter_text_kernel(
    const int* __restrict__ src_index, const int* __restrict__ input_ids,
    const float* __restrict__ embed, float* __restrict__ final_emb)
{
    int row = blockIdx.x;
    int src = src_index[row];
    if (src == -2) return;   // image row, written by GEMM3
    float4* dst = (float4*)(final_emb + (size_t)row * D_);
    if (src >= 0) {
        int b = row / MAXE_;
        int tok = input_ids[b * S_ + src];
        const float4* s = (const float4*)(embed + (size_t)tok * D_);
#pragma unroll
        for (int i = threadIdx.x; i < D_ / 4; i += 256) dst[i] = s[i];
    } else {
#pragma unroll
        for (int i = threadIdx.x; i < D_ / 4; i += 256)
            dst[i] = make_float4(0.f, 0.f, 0.f, 0.f);
    }
}

extern "C" void kernel_launch(void* const* d_in, const int* in_sizes, int n_in,
                              void* d_out, int out_size, void* d_ws, size_t ws_size,
                              hipStream_t stream)
{
    const int*   input_ids = (const int*)d_in[0];
    const float* pixel     = (const float*)d_in[1];
    const int*   attn      = (const int*)d_in[2];
    const int*   labels    = (const int*)d_in[3];
    const float* embed     = (const float*)d_in[4];
    const float* patch_w   = (const float*)d_in[6];
    const float* patch_b   = (const float*)d_in[7];
    const float* w1        = (const float*)d_in[8];
    const float* b1        = (const float*)d_in[9];
    const float* w2        = (const float*)d_in[10];
    const float* b2        = (const float*)d_in[11];
    float* out = (float*)d_out;

    // workspace layout (all 16B-aligned)
    char* w = (char*)d_ws;
    int* src_index = (int*)w;                                    // 51200 B
    int* img_pos   = (int*)(w + 51200);                          // 18432 B
    ushort_t* xh   = (ushort_t*)(w + 51200 + 18432);             // 4608*608 bf16
    ushort_t* xl   = xh  + (size_t)B_ * NP_ * KP_;               // 4608*608 bf16
    ushort_t* pwh  = xl  + (size_t)B_ * NP_ * KP_;               // 1024*608 bf16
    ushort_t* pwl  = pwh + (size_t)DV_ * KP_;                    // 1024*608 bf16
    ushort_t* hbuf = pwl + (size_t)DV_ * KP_;                    // 4608*1024 bf16
    ushort_t* g1   = hbuf + (size_t)B_ * NP_ * DV_;              // 4608*4096 bf16
    ushort_t* w1t  = g1 + (size_t)B_ * NP_ * D_;                 // 4096*1024 bf16
    ushort_t* w2t  = w1t + (size_t)D_ * DV_;                     // 4096*4096 bf16

    fill_tail_kernel<<<2048, 256, 0, stream>>>(out);
    merge_kernel<<<1, 512, 0, stream>>>(input_ids, attn, labels, out, src_index, img_pos);

    {
        int total = B_ * NP_ * KP_;
        patchify_split_kernel<<<(total + 255) / 256, 256, 0, stream>>>(pixel, xh, xl);
    }
    // patch_w (588x1024) -> hi/lo bf16 [1024][608]
    transpose_split_kernel<<<dim3(DV_ / 32, KP_ / 32), 256, 0, stream>>>(
        patch_w, pwh, pwl, PK_, DV_, KP_);
    // weight converts: w1 (DVxD) -> w1t (DxDV), w2 (DxD) -> w2t (DxD)
    transpose_bf16_kernel<<<dim3(D_ / 32, DV_ / 32), 256, 0, stream>>>(w1, w1t, DV_, D_);
    transpose_bf16_kernel<<<dim3(D_ / 32, D_ / 32), 256, 0, stream>>>(w2, w2t, D_, D_);

    const int M = B_ * NP_;  // 4608
    // GEMM1 (split bf16 MFMA, ~fp32 accurate): x @ patch_w + patch_b -> hbuf bf16
    mfma_gemm_split<<<dim3(DV_ / 128, M / 128), 256, 0, stream>>>(
        xh, xl, pwh, pwl, patch_b, hbuf, M, DV_, KP_);
    // GEMM2 (MFMA): gelu(h @ w1 + b1) -> g1 bf16
    mfma_gemm_bt<<<dim3(D_ / 128, M / 128), 256, 0, stream>>>(
        hbuf, w1t, b1, g1, nullptr, nullptr, M, D_, DV_, 1);
    // GEMM3 (MFMA): g1 @ w2 + b2 -> scattered fp32 rows of final_emb
    mfma_gemm_bt<<<dim3(D_ / 128, M / 128), 256, 0, stream>>>(
        g1, w2t, b2, nullptr, out + OFF_EMB, img_pos, M, D_, D_, 2);

    scatter_text_kernel<<<B_ * MAXE_, 256, 0, stream>>>(src_index, input_ids, embed, out + OFF_EMB);
}

// Round 6
// 1070.844 us; speedup vs baseline: 1.0371x; 1.0133x over previous
//
#include <hip/hip_runtime.h>
#include <math.h>

#define B_ 8
#define S_ 1024
#define D_ 4096
#define DV_ 1024
#define NP_ 576
#define MAXE_ 1599
#define PK_ 588          // 3*14*14
#define KP_ 608          // PK_ padded to multiple of 32
#define IMG_ 336
#define GRID_ 24
#define PATCH_ 14
#define IMAGE_TOKEN_ 32000
#define PAD_TOKEN_ 0
#define NLAYERS_ 32
#define NEXP_ 8
#define NSH_ 2

// ---- output layout (flat float32) ----
#define EMB_ELEMS ((size_t)B_ * MAXE_ * D_)
#define OFF_EMB   ((size_t)1)
#define OFF_ATTN  (OFF_EMB + EMB_ELEMS)
#define OFF_LAB   (OFF_ATTN + (size_t)B_ * MAXE_)
#define OFF_ROUTER (OFF_LAB + (size_t)B_ * MAXE_)
#define ROUTER_ELEMS ((size_t)NLAYERS_ * MAXE_ * (NEXP_ + NSH_))

typedef __bf16 bf16x8 __attribute__((ext_vector_type(8)));
typedef float  f32x4  __attribute__((ext_vector_type(4)));
typedef unsigned short ushort_t;

__device__ __forceinline__ unsigned short f2bf(float f) {
    unsigned u = __float_as_uint(f);
    u += 0x7fffu + ((u >> 16) & 1u);   // RNE
    return (unsigned short)(u >> 16);
}

__device__ __forceinline__ float bf2f(unsigned short u) {
    return __uint_as_float((unsigned)u << 16);
}

__device__ __forceinline__ void async_copy16(const void* g, void* l) {
    __builtin_amdgcn_global_load_lds(
        (const __attribute__((address_space(1))) void*)g,
        (__attribute__((address_space(3))) void*)l, 16, 0, 0);
}

// router zeros + all per-row defaults (parallel init moved out of 1-block merge)
__global__ void fill_tail_kernel(float* __restrict__ out,
                                 int* __restrict__ src_index,
                                 int* __restrict__ img_pos)
{
    size_t i = (size_t)blockIdx.x * blockDim.x + threadIdx.x;
    size_t stride = (size_t)gridDim.x * blockDim.x;
    if (i == 0) out[0] = 0.0f;
    for (size_t j = i; j < ROUTER_ELEMS; j += stride)
        out[OFF_ROUTER + j] = 0.0f;
    float* out_attn = out + OFF_ATTN;
    float* out_lab  = out + OFF_LAB;
    for (size_t j = i; j < (size_t)B_ * MAXE_; j += stride) {
        src_index[j] = -1;
        out_attn[j] = 0.0f;
        out_lab[j] = -100.0f;
    }
    for (size_t j = i; j < (size_t)B_ * NP_; j += stride)
        img_pos[j] = -1;
}

// Single block, 512 threads (8 waves). Wave w handles batch row w.
// Relies on fill_tail's defaults (src_index=-1, img_pos=-1, attn=0, lab=-100).
__global__ __launch_bounds__(512) void merge_kernel(
    const int* __restrict__ input_ids, const int* __restrict__ attn_mask,
    const int* __restrict__ labels, float* __restrict__ out,
    int* __restrict__ src_index, int* __restrict__ img_pos)
{
    __shared__ int sh_nbpad[B_];
    __shared__ int sh_shift[B_];
    __shared__ int sh_nqual[B_];
    __shared__ int sh_leftpad;
    float* out_attn = out + OFF_ATTN;
    float* out_lab  = out + OFF_LAB;
    const int tid = threadIdx.x;

    if (tid == 0) {
        int anypad = 0;
        for (int b = 0; b < B_; b++)
            if (input_ids[b * S_ + S_ - 1] == PAD_TOKEN_) anypad = 1;
        sh_leftpad = !anypad;
    }
    __syncthreads();

    const int wave = tid >> 6;
    const int lane = tid & 63;
    const unsigned long long below = (1ull << lane) - 1ull;

    if (wave < B_) {
        const int b = wave;
        int nspec = 0;
        for (int c = 0; c < S_; c += 64) {
            int id = input_ids[b * S_ + c + lane];
            nspec += __popcll(__ballot(id == IMAGE_TOKEN_));
        }
        int nb_pad = MAXE_ - S_ - (NP_ - 1) * nspec;
        int shift = sh_leftpad ? nb_pad : 0;
        int nholes = MAXE_ - (S_ - nspec);
        int nq = nholes - nb_pad; if (nq < 0) nq = 0;
        if (lane == 0) { sh_nbpad[b] = nb_pad; sh_shift[b] = shift; sh_nqual[b] = nq; }
        int carry = 0;
        for (int c = 0; c < S_; c += 64) {
            int t = c + lane;
            int id = input_ids[b * S_ + t];
            int spec = (id == IMAGE_TOKEN_);
            unsigned long long m = __ballot(spec);
            int nbefore = carry + __popcll(m & below);
            if (!spec) {
                int pos = t + (NP_ - 1) * nbefore + shift;
                if (pos >= 0 && pos < MAXE_) {
                    src_index[b * MAXE_ + pos] = t;
                    out_attn[b * MAXE_ + pos] = (float)attn_mask[b * S_ + t];
                    out_lab[b * MAXE_ + pos]  = (float)labels[b * S_ + t];
                }
            }
            carry += __popcll(m);
        }
    }
    __syncthreads();

    if (wave < B_) {
        const int b = wave;
        int offs = 0;
        for (int r = 0; r < b; r++) offs += sh_nqual[r];
        const int nb_pad = sh_nbpad[b];
        int hcarry = 0;
        for (int c = 0; c < MAXE_; c += 64) {
            int p = c + lane;
            int flag = 0;
            if (p < MAXE_) flag = (src_index[b * MAXE_ + p] == -1);
            unsigned long long m = __ballot(flag);
            int h = hcarry + __popcll(m & below);
            if (flag && h >= nb_pad) {
                int g = offs + (h - nb_pad);
                if (g > B_ * NP_ - 1) g = B_ * NP_ - 1;
                if (g < 0) g = 0;
                img_pos[g] = b * MAXE_ + p;
                src_index[b * MAXE_ + p] = -2;
                out_attn[b * MAXE_ + p] = 1.0f;
            }
            hcarry += __popcll(m);
        }
    }
}

// One fused prep kernel, block-partitioned:
//  [0, NPATCH)            : patchify + hi/lo split (elementwise)
//  [NPATCH, +NTS)         : transpose_split of patch_w -> pwh/pwl
//  [.., +NT1)             : transpose_bf16 of w1 -> w1t
//  [.., +NT2)             : transpose_bf16 of w2 -> w2t
#define NPATCH_BLOCKS ((B_ * NP_ * KP_ + 255) / 256)          // 10944
#define NTS_BLOCKS    ((DV_ / 32) * (KP_ / 32))               // 608
#define NT1_BLOCKS    ((D_ / 32) * (DV_ / 32))                // 4096
#define NT2_BLOCKS    ((D_ / 32) * (D_ / 32))                 // 16384
#define PREP_BLOCKS   (NPATCH_BLOCKS + NTS_BLOCKS + NT1_BLOCKS + NT2_BLOCKS)

__global__ __launch_bounds__(256) void prep_fused_kernel(
    const float* __restrict__ pix, ushort_t* __restrict__ xh, ushort_t* __restrict__ xl,
    const float* __restrict__ patch_w, ushort_t* __restrict__ pwh, ushort_t* __restrict__ pwl,
    const float* __restrict__ w1, ushort_t* __restrict__ w1t,
    const float* __restrict__ w2, ushort_t* __restrict__ w2t)
{
    __shared__ float tile[32][33];
    int bid = blockIdx.x;

    if (bid < NPATCH_BLOCKS) {
        // ---- patchify + fp32 -> (bf16 hi, bf16 lo) split, K padded to KP_ ----
        int i = bid * 256 + threadIdx.x;
        if (i >= B_ * NP_ * KP_) return;
        int q = i % KP_;
        int t = (i / KP_) % NP_;
        int n = i / (KP_ * NP_);
        float v = 0.0f;
        if (q < PK_) {
            int c = q / (PATCH_ * PATCH_);
            int r = q % (PATCH_ * PATCH_);
            int py = r / PATCH_, px = r % PATCH_;
            int gy = t / GRID_, gx = t % GRID_;
            v = pix[(((size_t)n * 3 + c) * IMG_ + gy * PATCH_ + py) * IMG_ + gx * PATCH_ + px];
        }
        ushort_t h = f2bf(v);
        xh[i] = h;
        xl[i] = f2bf(v - bf2f(h));
        return;
    }
    bid -= NPATCH_BLOCKS;

    if (bid < NTS_BLOCKS) {
        // ---- transpose + hi/lo split: patch_w[PK_][DV_] -> pwh/pwl [DV_][KP_] ----
        int bx = bid & 31;            // over C=DV_ (32 blocks)
        int by = bid >> 5;            // over RP=KP_ (19 blocks)
        int c0 = bx * 32, r0 = by * 32;
        int tx = threadIdx.x & 31, ty = threadIdx.x >> 5;   // 32 x 8
        for (int i = ty; i < 32; i += 8) {
            float v = 0.0f;
            if (r0 + i < PK_) v = patch_w[(size_t)(r0 + i) * DV_ + c0 + tx];
            tile[i][tx] = v;
        }
        __syncthreads();
        for (int i = ty; i < 32; i += 8) {
            if (r0 + tx < KP_) {
                float v = tile[tx][i];
                ushort_t h = f2bf(v);
                pwh[(size_t)(c0 + i) * KP_ + r0 + tx] = h;
                pwl[(size_t)(c0 + i) * KP_ + r0 + tx] = f2bf(v - bf2f(h));
            }
        }
        return;
    }
    bid -= NTS_BLOCKS;

    // ---- transpose + fp32->bf16: src[R][C] -> dst[C][R], ushort2 stores ----
    const float* src; ushort_t* dst; int R;
    if (bid < NT1_BLOCKS) {
        src = w1; dst = w1t; R = DV_;
    } else {
        bid -= NT1_BLOCKS;
        src = w2; dst = w2t; R = D_;
    }
    int bx = bid & 127;               // over C=D_ (128 blocks)
    int by = bid >> 7;                // over R
    int c0 = bx * 32, r0 = by * 32;
    int tx = threadIdx.x & 31, ty = threadIdx.x >> 5;       // 32 x 8
    for (int i = ty; i < 32; i += 8)
        tile[i][tx] = src[(size_t)(r0 + i) * D_ + c0 + tx];
    __syncthreads();
    int j = threadIdx.x & 15;
    int k = threadIdx.x >> 4;
#pragma unroll
    for (int p = 0; p < 2; p++) {
        int i = k + p * 16;
        ushort2 v;
        v.x = f2bf(tile[2 * j][i]);
        v.y = f2bf(tile[2 * j + 1][i]);
        *(ushort2*)&dst[(size_t)(c0 + i) * R + r0 + 2 * j] = v;
    }
}

// Split-precision MFMA GEMM (fp32-accurate via bf16 hi/lo, 3 passes):
// C[M][N] = (Ah+Al)[M][K] @ (Bh+Bl)[N][K]^T + bias, dropping Al*Bl (~2^-18 rel).
// 128x128 / BK=32 / 4-wave. bf16 output.
__global__ __launch_bounds__(256) void mfma_gemm_split(
    const ushort_t* __restrict__ Ah, const ushort_t* __restrict__ Al,
    const ushort_t* __restrict__ Bth, const ushort_t* __restrict__ Btl,
    const float* __restrict__ bias, ushort_t* __restrict__ outb,
    int M, int N, int K)
{
    __shared__ ushort_t Ash[128 * 32];
    __shared__ ushort_t Asl[128 * 32];
    __shared__ ushort_t Bsh[128 * 32];
    __shared__ ushort_t Bsl[128 * 32];
    const int tid  = threadIdx.x;
    const int wave = tid >> 6;
    const int lane = tid & 63;
    const int l16  = lane & 15;
    const int quad = lane >> 4;
    const int wrow = (wave >> 1) * 64;
    const int wcol = (wave & 1) * 64;
    const int row0 = blockIdx.y * 128;
    const int col0 = blockIdx.x * 128;

    f32x4 acc[4][4];
#pragma unroll
    for (int i = 0; i < 4; i++)
#pragma unroll
        for (int j = 0; j < 4; j++) acc[i][j] = (f32x4)(0.0f);

    const int R0a = wave * 32;
    const int lr  = lane >> 2;
    const int lc  = (lane & 3) * 8;

    for (int k0 = 0; k0 < K; k0 += 32) {
#pragma unroll
        for (int i = 0; i < 2; i++) {
            int R0 = R0a + i * 16;
            size_t aoff = (size_t)(row0 + R0 + lr) * K + k0 + lc;
            size_t boff = (size_t)(col0 + R0 + lr) * K + k0 + lc;
            async_copy16(Ah  + aoff, &Ash[R0 * 32]);
            async_copy16(Al  + aoff, &Asl[R0 * 32]);
            async_copy16(Bth + boff, &Bsh[R0 * 32]);
            async_copy16(Btl + boff, &Bsl[R0 * 32]);
        }
        __syncthreads();

        bf16x8 ah[4], al[4], bh[4], bl[4];
#pragma unroll
        for (int mt = 0; mt < 4; mt++) {
            ah[mt] = *(const bf16x8*)&Ash[(wrow + mt * 16 + l16) * 32 + quad * 8];
            al[mt] = *(const bf16x8*)&Asl[(wrow + mt * 16 + l16) * 32 + quad * 8];
        }
#pragma unroll
        for (int nt = 0; nt < 4; nt++) {
            bh[nt] = *(const bf16x8*)&Bsh[(wcol + nt * 16 + l16) * 32 + quad * 8];
            bl[nt] = *(const bf16x8*)&Bsl[(wcol + nt * 16 + l16) * 32 + quad * 8];
        }
#pragma unroll
        for (int mt = 0; mt < 4; mt++)
#pragma unroll
            for (int nt = 0; nt < 4; nt++) {
                acc[mt][nt] = __builtin_amdgcn_mfma_f32_16x16x32_bf16(
                    ah[mt], bh[nt], acc[mt][nt], 0, 0, 0);
                acc[mt][nt] = __builtin_amdgcn_mfma_f32_16x16x32_bf16(
                    ah[mt], bl[nt], acc[mt][nt], 0, 0, 0);
                acc[mt][nt] = __builtin_amdgcn_mfma_f32_16x16x32_bf16(
                    al[mt], bh[nt], acc[mt][nt], 0, 0, 0);
            }
        __syncthreads();
    }

    float bv[4];
#pragma unroll
    for (int nt = 0; nt < 4; nt++) bv[nt] = bias[col0 + wcol + nt * 16 + l16];

#pragma unroll
    for (int mt = 0; mt < 4; mt++) {
#pragma unroll
        for (int r = 0; r < 4; r++) {
            int row = row0 + wrow + mt * 16 + quad * 4 + r;
            ushort_t* dst = outb + (size_t)row * N;
#pragma unroll
            for (int nt = 0; nt < 4; nt++) {
                int col = col0 + wcol + nt * 16 + l16;
                dst[col] = f2bf(acc[mt][nt][r] + bv[nt]);
            }
        }
    }
}

// bf16 MFMA GEMM, B-transposed: C[M][N] = A[M][K] @ Bt[N][K]^T  (+bias)
// 128x128 tile, BK=32, 256 threads = 4 waves in 2x2, 16x16x32 MFMA.
// mode 1: gelu(acc+bias) -> bf16 outb ; mode 2: acc+bias -> f32 outf scattered
__global__ __launch_bounds__(256) void mfma_gemm_bt(
    const ushort_t* __restrict__ A, const ushort_t* __restrict__ Bt,
    const float* __restrict__ bias, ushort_t* __restrict__ outb,
    float* __restrict__ outf, const int* __restrict__ pos_map,
    int M, int N, int K, int mode)
{
    __shared__ ushort_t As[128 * 32];
    __shared__ ushort_t Bs[128 * 32];
    const int tid  = threadIdx.x;
    const int wave = tid >> 6;
    const int lane = tid & 63;
    const int l16  = lane & 15;
    const int quad = lane >> 4;
    const int wrow = (wave >> 1) * 64;
    const int wcol = (wave & 1) * 64;
    const int row0 = blockIdx.y * 128;
    const int col0 = blockIdx.x * 128;

    f32x4 acc[4][4];
#pragma unroll
    for (int i = 0; i < 4; i++)
#pragma unroll
        for (int j = 0; j < 4; j++) acc[i][j] = (f32x4)(0.0f);

    const int R0a = wave * 32;
    const int lr  = lane >> 2;
    const int lc  = (lane & 3) * 8;

    for (int k0 = 0; k0 < K; k0 += 32) {
#pragma unroll
        for (int i = 0; i < 2; i++) {
            int R0 = R0a + i * 16;
            const ushort_t* ga = A  + (size_t)(row0 + R0 + lr) * K + k0 + lc;
            const ushort_t* gb = Bt + (size_t)(col0 + R0 + lr) * K + k0 + lc;
            async_copy16(ga, &As[R0 * 32]);
            async_copy16(gb, &Bs[R0 * 32]);
        }
        __syncthreads();

        bf16x8 af[4], bf[4];
#pragma unroll
        for (int mt = 0; mt < 4; mt++)
            af[mt] = *(const bf16x8*)&As[(wrow + mt * 16 + l16) * 32 + quad * 8];
#pragma unroll
        for (int nt = 0; nt < 4; nt++)
            bf[nt] = *(const bf16x8*)&Bs[(wcol + nt * 16 + l16) * 32 + quad * 8];
#pragma unroll
        for (int mt = 0; mt < 4; mt++)
#pragma unroll
            for (int nt = 0; nt < 4; nt++)
                acc[mt][nt] = __builtin_amdgcn_mfma_f32_16x16x32_bf16(
                    af[mt], bf[nt], acc[mt][nt], 0, 0, 0);
        __syncthreads();
    }

    float bv[4];
#pragma unroll
    for (int nt = 0; nt < 4; nt++) bv[nt] = bias[col0 + wcol + nt * 16 + l16];

#pragma unroll
    for (int mt = 0; mt < 4; mt++) {
#pragma unroll
        for (int r = 0; r < 4; r++) {
            int row = row0 + wrow + mt * 16 + quad * 4 + r;
            if (mode == 2) {
                int orow = pos_map[row];
                if (orow < 0) continue;
#pragma unroll
                for (int nt = 0; nt < 4; nt++) {
                    int col = col0 + wcol + nt * 16 + l16;
                    outf[(size_t)orow * N + col] = acc[mt][nt][r] + bv[nt];
                }
            } else {
#pragma unroll
                for (int nt = 0; nt < 4; nt++) {
                    int col = col0 + wcol + nt * 16 + l16;
                    float x = acc[mt][nt][r] + bv[nt];
                    // gelu(tanh approx) == x * sigmoid(2u); one v_exp_f32
                    float u = 0.7978845608028654f * (x + 0.044715f * x * x * x);
                    x = x / (1.0f + __expf(-2.0f * u));
                    outb[(size_t)row * N + col] = f2bf(x);
                }
            }
        }
    }
}

__global__ __launch_bounds__(256) void scatter_text_kernel(
    const int* __restrict__ src_index, const int* __restrict__ input_ids,
    const float* __restrict__ embed, float* __restrict__ final_emb)
{
    int row = blockIdx.x;
    int src = src_index[row];
    if (src == -2) return;   // image row, written by GEMM3
    float4* dst = (float4*)(final_emb + (size_t)row * D_);
    if (src >= 0) {
        int b = row / MAXE_;
        int tok = input_ids[b * S_ + src];
        const float4* s = (const float4*)(embed + (size_t)tok * D_);
#pragma unroll
        for (int i = threadIdx.x; i < D_ / 4; i += 256) dst[i] = s[i];
    } else {
#pragma unroll
        for (int i = threadIdx.x; i < D_ / 4; i += 256)
            dst[i] = make_float4(0.f, 0.f, 0.f, 0.f);
    }
}

extern "C" void kernel_launch(void* const* d_in, const int* in_sizes, int n_in,
                              void* d_out, int out_size, void* d_ws, size_t ws_size,
                              hipStream_t stream)
{
    const int*   input_ids = (const int*)d_in[0];
    const float* pixel     = (const float*)d_in[1];
    const int*   attn      = (const int*)d_in[2];
    const int*   labels    = (const int*)d_in[3];
    const float* embed     = (const float*)d_in[4];
    const float* patch_w   = (const float*)d_in[6];
    const float* patch_b   = (const float*)d_in[7];
    const float* w1        = (const float*)d_in[8];
    const float* b1        = (const float*)d_in[9];
    const float* w2        = (const float*)d_in[10];
    const float* b2        = (const float*)d_in[11];
    float* out = (float*)d_out;

    // workspace layout (all 16B-aligned)
    char* w = (char*)d_ws;
    int* src_index = (int*)w;                                    // 51200 B
    int* img_pos   = (int*)(w + 51200);                          // 18432 B
    ushort_t* xh   = (ushort_t*)(w + 51200 + 18432);             // 4608*608 bf16
    ushort_t* xl   = xh  + (size_t)B_ * NP_ * KP_;               // 4608*608 bf16
    ushort_t* pwh  = xl  + (size_t)B_ * NP_ * KP_;               // 1024*608 bf16
    ushort_t* pwl  = pwh + (size_t)DV_ * KP_;                    // 1024*608 bf16
    ushort_t* hbuf = pwl + (size_t)DV_ * KP_;                    // 4608*1024 bf16
    ushort_t* g1   = hbuf + (size_t)B_ * NP_ * DV_;              // 4608*4096 bf16
    ushort_t* w1t  = g1 + (size_t)B_ * NP_ * D_;                 // 4096*1024 bf16
    ushort_t* w2t  = w1t + (size_t)D_ * DV_;                     // 4096*4096 bf16

    fill_tail_kernel<<<2048, 256, 0, stream>>>(out, src_index, img_pos);
    merge_kernel<<<1, 512, 0, stream>>>(input_ids, attn, labels, out, src_index, img_pos);

    // fused prep: patchify+split, patch_w transpose+split, w1/w2 transposes
    prep_fused_kernel<<<PREP_BLOCKS, 256, 0, stream>>>(
        pixel, xh, xl, patch_w, pwh, pwl, w1, w1t, w2, w2t);

    const int M = B_ * NP_;  // 4608
    // GEMM1 (split bf16 MFMA, ~fp32 accurate): x @ patch_w + patch_b -> hbuf bf16
    mfma_gemm_split<<<dim3(DV_ / 128, M / 128), 256, 0, stream>>>(
        xh, xl, pwh, pwl, patch_b, hbuf, M, DV_, KP_);
    // GEMM2 (MFMA): gelu(h @ w1 + b1) -> g1 bf16
    mfma_gemm_bt<<<dim3(D_ / 128, M / 128), 256, 0, stream>>>(
        hbuf, w1t, b1, g1, nullptr, nullptr, M, D_, DV_, 1);
    // GEMM3 (MFMA): g1 @ w2 + b2 -> scattered fp32 rows of final_emb
    mfma_gemm_bt<<<dim3(D_ / 128, M / 128), 256, 0, stream>>>(
        g1, w2t, b2, nullptr, out + OFF_EMB, img_pos, M, D_, D_, 2);

    scatter_text_kernel<<<B_ * MAXE_, 256, 0, stream>>>(src_index, input_ids, embed, out + OFF_EMB);
}